// Round 14
// baseline (774.310 us; speedup 1.0000x reference)
//
#include <hip/hip_runtime.h>
#include <hip/hip_bf16.h>

// Shapes (fixed for this problem)
#define BB   4
#define NQ   4096
#define MS   1024
#define CF   128
#define DD   256
#define PHH  64
#define AHH  512
#define KNN  16
#define EPSBN 1e-5f
#define LDH  72      // LDS stride for s_phb/s_hid (64 + 8 pad), ushorts
#define LKH  264     // LDS stride for kh key tile (256 + 8 pad)

typedef unsigned short ushort_t;
typedef __attribute__((ext_vector_type(8))) short bf16x8;
typedef __attribute__((ext_vector_type(4))) float floatx4;

__device__ __forceinline__ float u2f(ushort_t u) {
  return __uint_as_float(((unsigned int)u) << 16);
}
__device__ __forceinline__ ushort_t f2u(float f) {
  __hip_bfloat16 h = __float2bfloat16(f);
  return *(ushort_t*)&h;
}
// raw input read with inline dtype conversion (bit-identical to cvt output)
__device__ __forceinline__ float ldr(const void* p, int i, bool f32) {
  return f32 ? ((const float*)p)[i] : u2f(((const ushort_t*)p)[i]);
}

// ---------------------------------------------------------------------------
// K0: pre — cvt (blocks 0..511) ∪ cvtw (512..1023) ∪ prep (1024..1535).
// cvtw/prep read RAW inputs with inline conversion -> no dependency on cvt.
// ---------------------------------------------------------------------------
#define NSEG 30
struct CvtArgs {
  const void* src[NSEG];
  int cnt[NSEG];
  int off[NSEG];
};
struct RawArgs {
  const void* w1;    // attn_w1  (512x256)
  const void* w2;    // attn_w2  (256x512)
  const void* w2p;   // pos_w2   (256x64)
  const void* wq;    // w_query  (256x128)
  const void* bq;    // b_query  (256)
  const void* b2;    // pos_b2   (256)
  const void* ab1;   // attn_b1  (512)
};

__global__ __launch_bounds__(256) void pre_kernel(
    CvtArgs a, RawArgs r, float* __restrict__ dst,
    ushort_t* __restrict__ w1b, ushort_t* __restrict__ w2b,
    ushort_t* __restrict__ w2pb,
    ushort_t* __restrict__ WWb, ushort_t* __restrict__ WQHb,
    float* __restrict__ ballf,
    const ushort_t* __restrict__ probe) {
  const bool f32 = (probe[0] == 0);
  const int blk = blockIdx.x;
  const int tid = threadIdx.x;

  if (blk < 512) {
    // ---- cvt: dtype-normalization to fp32 (proven) ----
    const int gid = blk * 256 + tid;
    const int gsz = 512 * 256;
    for (int s = 0; s < NSEG; ++s) {
      float* d = dst + a.off[s];
      const int n = a.cnt[s];
      if (f32) {
        const float* sp = (const float*)a.src[s];
        for (int i = gid; i < n; i += gsz) d[i] = sp[i];
      } else {
        const ushort_t* sp = (const ushort_t*)a.src[s];
        for (int i = gid; i < n; i += gsz) d[i] = u2f(sp[i]);
      }
    }
  } else if (blk < 1024) {
    // ---- cvtw: bf16 copies of attn_w1 / attn_w2 / pos_w2 (raw reads) ----
    const int i = (blk - 512) * 256 + tid;   // covers 131072
    w1b[i] = f2u(ldr(r.w1, i, f32));
    w2b[i] = f2u(ldr(r.w2, i, f32));
    if (i < DD * PHH) w2pb[i] = f2u(ldr(r.w2p, i, f32));
  } else {
    // ---- prep: folded matrices (raw reads; identical arithmetic) ----
    __shared__ float s_w1[DD];
    const int aa = blk - 1024;        // 512 rows
    if (tid < 128) {
      s_w1[tid] = ldr(r.w1, aa * DD + tid, f32);
      s_w1[tid + 128] = ldr(r.w1, aa * DD + tid + 128, f32);
    }
    __syncthreads();
    if (tid < 128) {
      float acc = 0.f;
      for (int d = 0; d < DD; ++d) acc += s_w1[d] * ldr(r.wq, d * CF + tid, f32);
      WQHb[aa * CF + tid] = f2u(acc);
      if (tid < PHH) {
        float acc2 = 0.f;
        for (int d = 0; d < DD; ++d) acc2 += s_w1[d] * ldr(r.w2p, d * PHH + tid, f32);
        WWb[aa * PHH + tid] = f2u(acc2);
      }
      if (tid == 0) {
        float acc3 = ldr(r.ab1, aa, f32);
        for (int d = 0; d < DD; ++d)
          acc3 += s_w1[d] * (ldr(r.bq, d, f32) + ldr(r.b2, d, f32));
        ballf[aa] = acc3;
      }
    }
  }
}

// ---------------------------------------------------------------------------
// K1: fused value -> key/val (bf16 out). Proven; unchanged.
// ---------------------------------------------------------------------------
__global__ __launch_bounds__(256) void vkv_kernel(
    const float* __restrict__ w_start, const float* __restrict__ b_start,
    const float* __restrict__ w_key, const float* __restrict__ b_key,
    const float* __restrict__ w_value, const float* __restrict__ b_value,
    const float* __restrict__ seed_fea,
    ushort_t* __restrict__ key_b, ushort_t* __restrict__ val_b) {
  __shared__ __align__(16) float s_val[4][DD];
  const int tid = threadIdx.x;              // = d
  const int b = blockIdx.x >> 8;
  const int m0 = (blockIdx.x & 255) << 2;

  float a0 = b_start[tid], a1 = a0, a2 = a0, a3 = a0;
  {
    const float* wrow = w_start + tid * CF;
    const float* colb = seed_fea + b * CF * MS + m0;
    for (int c = 0; c < CF; c += 4) {
      float4 w = *(const float4*)(wrow + c);
      float4 f0 = *(const float4*)(colb + (c + 0) * MS);
      float4 f1 = *(const float4*)(colb + (c + 1) * MS);
      float4 f2 = *(const float4*)(colb + (c + 2) * MS);
      float4 f3 = *(const float4*)(colb + (c + 3) * MS);
      a0 += w.x * f0.x + w.y * f1.x + w.z * f2.x + w.w * f3.x;
      a1 += w.x * f0.y + w.y * f1.y + w.z * f2.y + w.w * f3.y;
      a2 += w.x * f0.z + w.y * f1.z + w.z * f2.z + w.w * f3.z;
      a3 += w.x * f0.w + w.y * f1.w + w.z * f2.w + w.w * f3.w;
    }
  }
  s_val[0][tid] = a0; s_val[1][tid] = a1; s_val[2][tid] = a2; s_val[3][tid] = a3;
  __syncthreads();

  float ak[4], av[4];
#pragma unroll
  for (int i = 0; i < 4; ++i) { ak[i] = b_key[tid]; av[i] = b_value[tid]; }
  {
    const float* kr = w_key + tid * DD;
    const float* vr = w_value + tid * DD;
    for (int c = 0; c < DD; c += 4) {
      float4 ku = *(const float4*)(kr + c);
      float4 vu = *(const float4*)(vr + c);
      float4 v0 = *(const float4*)(&s_val[0][c]);
      float4 v1 = *(const float4*)(&s_val[1][c]);
      float4 v2 = *(const float4*)(&s_val[2][c]);
      float4 v3 = *(const float4*)(&s_val[3][c]);
      ak[0] += ku.x * v0.x + ku.y * v0.y + ku.z * v0.z + ku.w * v0.w;
      ak[1] += ku.x * v1.x + ku.y * v1.y + ku.z * v1.z + ku.w * v1.w;
      ak[2] += ku.x * v2.x + ku.y * v2.y + ku.z * v2.z + ku.w * v2.w;
      ak[3] += ku.x * v3.x + ku.y * v3.y + ku.z * v3.z + ku.w * v3.w;
      av[0] += vu.x * v0.x + vu.y * v0.y + vu.z * v0.z + vu.w * v0.w;
      av[1] += vu.x * v1.x + vu.y * v1.y + vu.z * v1.z + vu.w * v1.w;
      av[2] += vu.x * v2.x + vu.y * v2.y + vu.z * v2.z + vu.w * v2.w;
      av[3] += vu.x * v3.x + vu.y * v3.y + vu.z * v3.z + vu.w * v3.w;
    }
  }
#pragma unroll
  for (int i = 0; i < 4; ++i) {
    key_b[(b * MS + m0 + i) * DD + tid] = f2u(ak[i]);
    val_b[(b * MS + m0 + i) * DD + tid] = f2u(av[i]);
  }
}

// ---------------------------------------------------------------------------
// K2: khknn — kh (blocks 0..255, tid<256 active) ∪ knn (blocks 256..2303).
// Bodies identical to proven kh_kernel / knn_kernel; LDS unioned.
// ---------------------------------------------------------------------------
__global__ __launch_bounds__(512) void khknn_kernel(
    const ushort_t* __restrict__ key_b, const ushort_t* __restrict__ w1b,
    ushort_t* __restrict__ khb,
    const float* __restrict__ pos_flipped, const float* __restrict__ seed,
    int* __restrict__ idx_out) {
  __shared__ __align__(16) float s_mem[MS * 3];   // 12288 B (>= kh's 8448 B)
  const int tid = threadIdx.x;

  if (blockIdx.x < 256) {
    // ---- kh: kh[b][m][a] = key[m] . W1[a] ----
    ushort_t* s_key = (ushort_t*)s_mem;
    const int b = blockIdx.x >> 6;
    const int m0 = (blockIdx.x & 63) << 4;
    if (tid < 256) {
      const int row = tid >> 4, seg = tid & 15;
      const ushort_t* src = key_b + (b * MS + m0 + row) * DD + seg * 16;
      ushort_t* dst = s_key + row * LKH + seg * 16;
      *(bf16x8*)(dst + 0) = *(const bf16x8*)(src + 0);
      *(bf16x8*)(dst + 8) = *(const bf16x8*)(src + 8);
    }
    __syncthreads();
    if (tid < 256) {
      const int wv = tid >> 6, ln = tid & 63;
      const int qu = ln >> 4, l15 = ln & 15;
      bf16x8 af[8];
#pragma unroll
      for (int ks = 0; ks < 8; ++ks)
        af[ks] = *(const bf16x8*)(s_key + l15 * LKH + ks * 32 + qu * 8);
      floatx4 acc[8];
#pragma unroll
      for (int nt = 0; nt < 8; ++nt) acc[nt] = (floatx4){0.f, 0.f, 0.f, 0.f};
#pragma unroll
      for (int ks = 0; ks < 8; ++ks)
#pragma unroll
        for (int nt = 0; nt < 8; ++nt) {
          bf16x8 bfr = *(const bf16x8*)(w1b + (wv * 128 + nt * 16 + l15) * DD + ks * 32 + qu * 8);
          acc[nt] = __builtin_amdgcn_mfma_f32_16x16x32_bf16(af[ks], bfr, acc[nt], 0, 0, 0);
        }
#pragma unroll
      for (int nt = 0; nt < 8; ++nt)
#pragma unroll
        for (int r = 0; r < 4; ++r)
          khb[(b * MS + m0 + qu * 4 + r) * AHH + wv * 128 + nt * 16 + l15] = f2u(acc[nt][r]);
    }
    return;
  }

  // ---- knn: WAVE-PER-QUERY, 8 queries/block (proven R6) ----
  const int bk = blockIdx.x - 256;
  const int wv = tid >> 6, ln = tid & 63;
  const int b = bk >> 9;                     // 512 blocks per batch
  const int q = ((bk & 511) << 3) + wv;

  for (int i = tid; i < MS * 3; i += 512) s_mem[i] = seed[b * MS * 3 + i];
  __syncthreads();

  const float qx = pos_flipped[(b * NQ + q) * 3 + 0];
  const float qy = pos_flipped[(b * NQ + q) * 3 + 1];
  const float qz = pos_flipped[(b * NQ + q) * 3 + 2];
  const float q2 = qx * qx + qy * qy + qz * qz;

  unsigned long long key[16];
#pragma unroll
  for (int t = 0; t < 16; ++t) {
    int j = ln + (t << 6);
    float x = s_mem[j * 3 + 0], y = s_mem[j * 3 + 1], z = s_mem[j * 3 + 2];
    float r2 = x * x + y * y + z * z;
    float dist = q2 + r2 - 2.0f * (qx * x + qy * y + qz * z);
    unsigned u = __float_as_uint(dist);
    u ^= (u >> 31) ? 0xFFFFFFFFu : 0x80000000u;   // monotone float->uint
    key[t] = ((unsigned long long)u << 10) | (unsigned)j;
  }

#pragma unroll 1
  for (int r = 0; r < KNN; ++r) {
    unsigned long long m = key[0];
#pragma unroll
    for (int t = 1; t < 16; ++t) m = (key[t] < m) ? key[t] : m;
#pragma unroll
    for (int off = 32; off >= 1; off >>= 1) {
      unsigned lo = (unsigned)m, hi = (unsigned)(m >> 32);
      unsigned olo = __shfl_xor((int)lo, off);
      unsigned ohi = __shfl_xor((int)hi, off);
      unsigned long long o = ((unsigned long long)ohi << 32) | olo;
      m = (o < m) ? o : m;
    }
    if (ln == 0) idx_out[(b * NQ + q) * KNN + r] = (int)(m & 1023u);
#pragma unroll
    for (int t = 0; t < 16; ++t) key[t] = (key[t] == m) ? ~0ull : key[t];
  }
}

// ---------------------------------------------------------------------------
// K3: FUSED pipeline — byte-identical to R13 (proven 464 µs): distributed-W1
// gemm1 (K=64) + kh table + dbuf s_hid (one barrier per nc). Macros not
// lambdas (R11 scratch trap). 4 blocks/CU.
// ---------------------------------------------------------------------------
#define DO_B(NCX, HID)                                                         \
  {                                                                            \
    const int nc_ = (NCX);                                                     \
    floatx4 accb[4];                                                           \
    _Pragma("unroll")                                                          \
    for (int mt = 0; mt < 4; ++mt) accb[mt] = (floatx4){0.f, 0.f, 0.f, 0.f};   \
    _Pragma("unroll")                                                          \
    for (int ks = 0; ks < 2; ++ks) {                                           \
      bf16x8 bw = *(const bf16x8*)(WWb + (nc_ * 64 + wv * 16 + l15) * PHH +    \
                                   ks * 32 + qu * 8);                          \
      _Pragma("unroll")                                                        \
      for (int mt = 0; mt < 4; ++mt) {                                         \
        bf16x8 af = *(const bf16x8*)(s_phb + (mt * 16 + l15) * LDH +           \
                                     ks * 32 + qu * 8);                        \
        accb[mt] = __builtin_amdgcn_mfma_f32_16x16x32_bf16(af, bw, accb[mt],   \
                                                           0, 0, 0);           \
      }                                                                        \
    }                                                                          \
    const int a_ = nc_ * 64 + wv * 16 + l15;                                   \
    float inv_ = attn_g1[a_] * rsqrtf(attn_var1[a_] + EPSBN);                  \
    float offc_ = ballf[a_] * inv_ + attn_beta1[a_] - attn_mu1[a_] * inv_;     \
    _Pragma("unroll")                                                          \
    for (int mt = 0; mt < 4; ++mt) {                                           \
      const float qhv_ = s_qh[mt * AHH + a_];                                  \
      _Pragma("unroll")                                                        \
      for (int r = 0; r < 4; ++r) {                                            \
        const int row_ = mt * 16 + qu * 4 + r;                                 \
        float khv_ = u2f(khb[(b * MS + s_idx[row_]) * AHH + a_]);              \
        float raw_ = accb[mt][r] + qhv_ - khv_;                                \
        (HID)[row_ * LDH + wv * 16 + l15] =                                    \
            f2u(fmaxf(raw_ * inv_ + offc_, 0.0f));                             \
      }                                                                        \
    }                                                                          \
  }

#define DO_C(NCX, HID)                                                         \
  {                                                                            \
    const int nc_ = (NCX);                                                     \
    _Pragma("unroll")                                                          \
    for (int ks = 0; ks < 2; ++ks) {                                           \
      bf16x8 af2[4];                                                           \
      _Pragma("unroll")                                                        \
      for (int mt = 0; mt < 4; ++mt)                                           \
        af2[mt] = *(const bf16x8*)((HID) + (mt * 16 + l15) * LDH +             \
                                   ks * 32 + qu * 8);                          \
      _Pragma("unroll")                                                        \
      for (int nt = 0; nt < 4; ++nt) {                                         \
        bf16x8 bfr = *(const bf16x8*)(w2b + (wv * 64 + nt * 16 + l15) * AHH +  \
                                      nc_ * 64 + ks * 32 + qu * 8);            \
        _Pragma("unroll")                                                      \
        for (int mt = 0; mt < 4; ++mt)                                         \
          accl[mt][nt] = __builtin_amdgcn_mfma_f32_16x16x32_bf16(              \
              af2[mt], bfr, accl[mt][nt], 0, 0, 0);                            \
      }                                                                        \
    }                                                                          \
  }

__global__ __launch_bounds__(256, 4) void fused_kernel(
    const float* __restrict__ pos, const float* __restrict__ seed,
    const void* __restrict__ fea_raw,
    const float* __restrict__ pos_w1, const float* __restrict__ pos_b1,
    const float* __restrict__ pos_g1, const float* __restrict__ pos_beta1,
    const float* __restrict__ pos_mu1, const float* __restrict__ pos_var1,
    const ushort_t* __restrict__ w2pb, const float* __restrict__ pos_b2,
    const float* __restrict__ attn_g1, const float* __restrict__ attn_beta1,
    const float* __restrict__ attn_mu1, const float* __restrict__ attn_var1,
    const float* __restrict__ ballf,
    const ushort_t* __restrict__ WWb, const ushort_t* __restrict__ WQHb,
    const ushort_t* __restrict__ w2b, const ushort_t* __restrict__ khb,
    const ushort_t* __restrict__ val_b,
    const int* __restrict__ idx_in,
    const float* __restrict__ w_end, const float* __restrict__ b_end,
    void* __restrict__ out_raw, const ushort_t* __restrict__ probe) {
  __shared__ __align__(16) ushort_t s_phb[64 * LDH];   // 9216 B (alive to AGG)
  __shared__ __align__(16) ushort_t s_hid0[64 * LDH];  // 9216 B (dbuf 0)
  __shared__ __align__(16) ushort_t s_hid1[64 * LDH];  // 9216 B (dbuf 1)
  __shared__ __align__(16) float s_qh[4 * AHH];        // 8192 B (aliased by s_agg)
  __shared__ __align__(16) ushort_t s_feab[4 * CF];    // 1024 B
  __shared__ float s_h[64 * 4];                        // 1024 B
  __shared__ int s_idx[64];                            //  256 B
  // total 37,344 B -> 4 blocks/CU (149.4 KB of 160)

  float* s_agg = s_qh;   // alias: s_qh dead after nc-loop

  const int tid = threadIdx.x;
  const int wv = tid >> 6;
  const int ln = tid & 63;
  const int qu = ln >> 4, l15 = ln & 15;
  const bool f32io = (probe[0] == 0);
  const int q0 = blockIdx.x * 4;            // 4 queries/block; batch never splits
  const int b = q0 >> 12;
  const int qn0 = q0 & (NQ - 1);

  // ---- P0: neighbor idx + h = [dis, rel] (tid<64) ; FEA stage (tid<128) ----
  if (tid < 64) {
    const int g = tid >> 4;
    const int qn = qn0 + g;
    const int j = idx_in[(q0 + g) * KNN + (tid & 15)];
    s_idx[tid] = j;
    float px = pos[(b * 3 + 0) * NQ + qn];
    float py = pos[(b * 3 + 1) * NQ + qn];
    float pz = pos[(b * 3 + 2) * NQ + qn];
    float rx = px - seed[(b * MS + j) * 3 + 0];
    float ry = py - seed[(b * MS + j) * 3 + 1];
    float rz = pz - seed[(b * MS + j) * 3 + 2];
    float dis = sqrtf(rx * rx + ry * ry + rz * rz);
    s_h[tid * 4 + 0] = dis;
    s_h[tid * 4 + 1] = rx;
    s_h[tid * 4 + 2] = ry;
    s_h[tid * 4 + 3] = rz;
  }
  if (tid < 128) {               // fea columns qn0..qn0+3 for channel c=tid
    const int c = tid;
    if (f32io) {
      const float* fc = (const float*)fea_raw + (size_t)b * CF * NQ + (size_t)c * NQ + qn0;
      float4 v = *(const float4*)fc;
      s_feab[0 * CF + c] = f2u(v.x);
      s_feab[1 * CF + c] = f2u(v.y);
      s_feab[2 * CF + c] = f2u(v.z);
      s_feab[3 * CF + c] = f2u(v.w);
    } else {
      const ushort_t* fc = (const ushort_t*)fea_raw + (size_t)b * CF * NQ + (size_t)c * NQ + qn0;
      unsigned long long v = *(const unsigned long long*)fc;
      s_feab[0 * CF + c] = (ushort_t)(v);
      s_feab[1 * CF + c] = (ushort_t)(v >> 16);
      s_feab[2 * CF + c] = (ushort_t)(v >> 32);
      s_feab[3 * CF + c] = (ushort_t)(v >> 48);
    }
  }
  __syncthreads();

  // ---- P1: s_phb = relu(BN(pos_w1 @ h)) (bf16), 64 rows x 64 p ----
  {
    const int p = tid & 63, kb = tid >> 6;
    float4 w = *(const float4*)(pos_w1 + p * 4);
    float inv = pos_g1[p] * rsqrtf(pos_var1[p] + EPSBN);
    float off = pos_b1[p] * inv + pos_beta1[p] - pos_mu1[p] * inv;
#pragma unroll
    for (int i = 0; i < 16; ++i) {
      int gk = kb * 16 + i;
      float raw = w.x * s_h[gk * 4 + 0] + w.y * s_h[gk * 4 + 1] +
                  w.z * s_h[gk * 4 + 2] + w.w * s_h[gk * 4 + 3];
      s_phb[gk * LDH + p] = f2u(fmaxf(raw * inv + off, 0.0f));
    }
  }

  // ---- QH: qh[4][512] = fea(4x128) @ WQH^T via MFMA (32 MFMA/wave) ----
  {
    bf16x8 afq[4];
#pragma unroll
    for (int ks = 0; ks < 4; ++ks) {
      if (l15 < 4) afq[ks] = *(const bf16x8*)(s_feab + l15 * CF + ks * 32 + qu * 8);
      else afq[ks] = (bf16x8){0, 0, 0, 0, 0, 0, 0, 0};
    }
    floatx4 aq[8];
#pragma unroll
    for (int nt = 0; nt < 8; ++nt) aq[nt] = (floatx4){0.f, 0.f, 0.f, 0.f};
#pragma unroll
    for (int ks = 0; ks < 4; ++ks)
#pragma unroll
      for (int nt = 0; nt < 8; ++nt) {
        bf16x8 bfr = *(const bf16x8*)(WQHb + (nt * 64 + wv * 16 + l15) * CF + ks * 32 + qu * 8);
        aq[nt] = __builtin_amdgcn_mfma_f32_16x16x32_bf16(afq[ks], bfr, aq[nt], 0, 0, 0);
      }
    if (qu == 0) {
#pragma unroll
      for (int nt = 0; nt < 8; ++nt)
#pragma unroll
        for (int r = 0; r < 4; ++r)
          s_qh[r * AHH + nt * 64 + wv * 16 + l15] = aq[nt][r];
    }
  }
  __syncthreads();

  // ---- nc-loop (dbuf): prologue B(0); then {B(nc+1) || C(nc); bar} x8 ----
  floatx4 accl[4][4];  // logits: rows mt*16+qu*4+r, cols wv*64+nt*16+l15
#pragma unroll
  for (int mt = 0; mt < 4; ++mt)
#pragma unroll
    for (int nt = 0; nt < 4; ++nt) accl[mt][nt] = (floatx4){0.f, 0.f, 0.f, 0.f};

  DO_B(0, s_hid0);
  __syncthreads();

#pragma unroll 1
  for (int nc = 0; nc < 8; ++nc) {
    ushort_t* cur = (nc & 1) ? s_hid1 : s_hid0;
    ushort_t* nxt = (nc & 1) ? s_hid0 : s_hid1;
    if (nc < 7) DO_B(nc + 1, nxt);
    DO_C(nc, cur);
    __syncthreads();   // B(nc+1) visible for next C; C(nc) done before B(nc+2)
  }

  // ---- AGG: softmax over k + pe RECOMPUTE (MFMA from s_phb) + val gather ----
#pragma unroll
  for (int nt = 0; nt < 4; ++nt) {
    const int c = wv * 64 + nt * 16 + l15;
    floatx4 ap[4];
#pragma unroll
    for (int mt = 0; mt < 4; ++mt) ap[mt] = (floatx4){0.f, 0.f, 0.f, 0.f};
#pragma unroll
    for (int ks = 0; ks < 2; ++ks) {
      bf16x8 bfr = *(const bf16x8*)(w2pb + c * PHH + ks * 32 + qu * 8);
#pragma unroll
      for (int mt = 0; mt < 4; ++mt) {
        bf16x8 af = *(const bf16x8*)(s_phb + (mt * 16 + l15) * LDH + ks * 32 + qu * 8);
        ap[mt] = __builtin_amdgcn_mfma_f32_16x16x32_bf16(af, bfr, ap[mt], 0, 0, 0);
      }
    }
    const float b2v = pos_b2[c];
#pragma unroll
    for (int mt = 0; mt < 4; ++mt) {
      float l0 = accl[mt][nt][0], l1 = accl[mt][nt][1];
      float l2 = accl[mt][nt][2], l3 = accl[mt][nt][3];
      float mx = fmaxf(fmaxf(l0, l1), fmaxf(l2, l3));
      mx = fmaxf(mx, __shfl_xor(mx, 16));
      mx = fmaxf(mx, __shfl_xor(mx, 32));
      float e0 = expf(l0 - mx), e1 = expf(l1 - mx);
      float e2 = expf(l2 - mx), e3 = expf(l3 - mx);
      float s = e0 + e1 + e2 + e3;
      s += __shfl_xor(s, 16);
      s += __shfl_xor(s, 32);
      const int row0 = mt * 16 + qu * 4;
      float v0 = u2f(val_b[(b * MS + s_idx[row0 + 0]) * DD + c]);
      float v1 = u2f(val_b[(b * MS + s_idx[row0 + 1]) * DD + c]);
      float v2 = u2f(val_b[(b * MS + s_idx[row0 + 2]) * DD + c]);
      float v3 = u2f(val_b[(b * MS + s_idx[row0 + 3]) * DD + c]);
      float p = e0 * (v0 + ap[mt][0] + b2v) + e1 * (v1 + ap[mt][1] + b2v) +
                e2 * (v2 + ap[mt][2] + b2v) + e3 * (v3 + ap[mt][3] + b2v);
      p += __shfl_xor(p, 16);
      p += __shfl_xor(p, 32);
      if (ln < 16) s_agg[mt * DD + c] = p / s;   // into s_qh alias
    }
  }
  __syncthreads();

  // ---- OUT: out = w_end @ agg + b_end + fea (2 queries per thread) ----
  {
    const int c = tid & 127;
    const int qh = tid >> 7;  // handles queries qh and qh+2
    float acc0 = 0.0f, acc1 = 0.0f;
    const float* wr = w_end + c * DD;
    for (int d = 0; d < DD; d += 4) {
      float4 w4 = *(const float4*)(wr + d);
      float4 a0 = *(const float4*)(s_agg + (qh + 0) * DD + d);
      float4 a1 = *(const float4*)(s_agg + (qh + 2) * DD + d);
      acc0 += w4.x * a0.x + w4.y * a0.y + w4.z * a0.z + w4.w * a0.w;
      acc1 += w4.x * a1.x + w4.y * a1.y + w4.z * a1.z + w4.w * a1.w;
    }
    const float be = b_end[c];
#pragma unroll
    for (int t = 0; t < 2; ++t) {
      const int q = qh + t * 2;
      const float accv = (t == 0) ? acc0 : acc1;
      const int oidx = (b * CF + c) * NQ + qn0 + q;
      float fres = f32io ? ((const float*)fea_raw)[oidx]
                         : u2f(((const ushort_t*)fea_raw)[oidx]);
      float v = accv + be + fres;
      if (f32io) ((float*)out_raw)[oidx] = v;
      else ((ushort_t*)out_raw)[oidx] = f2u(v);
    }
  }
}

// ---------------------------------------------------------------------------
extern "C" void kernel_launch(void* const* d_in, const int* in_sizes, int n_in,
                              void* d_out, int out_size, void* d_ws, size_t ws_size,
                              hipStream_t stream) {
  (void)in_sizes; (void)n_in; (void)out_size; (void)ws_size;

  // ws layout (float offsets)
  float* wsf = (float*)d_ws;
  ushort_t* key_b = (ushort_t*)wsf;                 // 1,048,576 ush
  ushort_t* val_b = (ushort_t*)(wsf + 524288);      // 1,048,576 ush
  int*      idxw  = (int*)(wsf + 1048576);          //   262,144 i
  float*    nrm   = wsf + 1310720;                  // 1,147,584 f
  ushort_t* w1b   = (ushort_t*)(wsf + 2458304);     //   131,072 ush
  ushort_t* w2b   = (ushort_t*)(wsf + 2523840);     //   131,072 ush
  ushort_t* w2pb  = (ushort_t*)(wsf + 2589376);     //    16,384 ush
  ushort_t* khb   = (ushort_t*)(wsf + 2613952);     // 2,097,152 ush (4 MB)
  ushort_t* WWb   = (ushort_t*)(wsf + 3662528);     //    32,768 ush
  ushort_t* WQHb  = (ushort_t*)(wsf + 3678912);     //    65,536 ush
  float*    ballf = wsf + 3711680;                  //       512 f
  // end: 3,712,192 f = 14,848,768 B

  static const int seg_in[NSEG] = {0, 1, 3, 4, 5, 6, 7, 8, 9, 10, 11, 12, 13, 14,
                                   15, 16, 17, 18, 19, 20, 21, 22, 23, 24, 25, 26,
                                   27, 28, 29, 30};
  static const int seg_cnt[NSEG] = {
      49152, 49152, 12288, 524288, 32768, 256, 65536, 256, 65536, 256,
      32768, 256, 256, 64, 64, 64, 64, 64, 16384, 256,
      131072, 512, 512, 512, 512, 512, 131072, 256, 32768, 128};
  static const int seg_off[NSEG] = {
      0, 49152, 98304, 110592, 634880, 667648, 667904, 733440, 733696, 799232,
      799488, 832256, 832512, 832768, 832832, 832896, 832960, 833024, 833088, 849472,
      849728, 980800, 981312, 981824, 982336, 982848, 983360, 1114432, 1114688, 1147456};

  CvtArgs ca;
  for (int s = 0; s < NSEG; ++s) {
    ca.src[s] = d_in[seg_in[s]];
    ca.cnt[s] = seg_cnt[s];
    ca.off[s] = seg_off[s];
  }
  RawArgs ra;
  ra.w1  = d_in[21];   // attn_w1
  ra.w2  = d_in[27];   // attn_w2
  ra.w2p = d_in[19];   // pos_w2
  ra.wq  = d_in[11];   // w_query
  ra.bq  = d_in[12];   // b_query
  ra.b2  = d_in[20];   // pos_b2
  ra.ab1 = d_in[22];   // attn_b1
  const ushort_t* probe = (const ushort_t*)d_in[18];  // pos_var1 (== 1.0)

  const float* posN      = nrm + 0;
  const float* pos_flipN = nrm + 49152;
  const float* seedN     = nrm + 98304;
  const float* seed_feaN = nrm + 110592;
  const float* w_startN  = nrm + 634880;
  const float* b_startN  = nrm + 667648;
  const float* w_keyN    = nrm + 667904;
  const float* b_keyN    = nrm + 733440;
  const float* w_valueN  = nrm + 733696;
  const float* b_valueN  = nrm + 799232;
  const float* pos_w1N   = nrm + 832512;
  const float* pos_b1N   = nrm + 832768;
  const float* pos_g1N   = nrm + 832832;
  const float* pos_beta1N= nrm + 832896;
  const float* pos_mu1N  = nrm + 832960;
  const float* pos_var1N = nrm + 833024;
  const float* pos_b2N   = nrm + 849472;
  const float* attn_g1N  = nrm + 981312;
  const float* attn_beta1N = nrm + 981824;
  const float* attn_mu1N = nrm + 982336;
  const float* attn_var1N= nrm + 982848;
  const float* w_endN    = nrm + 1114688;
  const float* b_endN    = nrm + 1147456;

  pre_kernel<<<1536, 256, 0, stream>>>(ca, ra, nrm, w1b, w2b, w2pb,
                                       WWb, WQHb, ballf, probe);
  vkv_kernel<<<BB * MS / 4, 256, 0, stream>>>(w_startN, b_startN, w_keyN, b_keyN,
                                              w_valueN, b_valueN, seed_feaN,
                                              key_b, val_b);
  khknn_kernel<<<256 + BB * NQ / 8, 512, 0, stream>>>(key_b, w1b, khb,
                                                      pos_flipN, seedN, idxw);
  fused_kernel<<<BB * NQ / 4, 256, 0, stream>>>(
      posN, seedN, d_in[2],
      pos_w1N, pos_b1N, pos_g1N, pos_beta1N, pos_mu1N, pos_var1N,
      w2pb, pos_b2N,
      attn_g1N, attn_beta1N, attn_mu1N, attn_var1N,
      ballf, WWb, WQHb, w2b, khb, val_b, idxw,
      w_endN, b_endN, d_out, probe);
}

// Round 15
// 729.420 us; speedup vs baseline: 1.0615x; 1.0615x over previous
//
#include <hip/hip_runtime.h>
#include <hip/hip_bf16.h>

// Shapes (fixed for this problem)
#define BB   4
#define NQ   4096
#define MS   1024
#define CF   128
#define DD   256
#define PHH  64
#define AHH  512
#define KNN  16
#define EPSBN 1e-5f
#define LDH  72      // LDS stride for s_phb/s_hid (64 + 8 pad), ushorts
#define LKH  264     // LDS stride for kh_kernel key tile (256 + 8 pad)

typedef unsigned short ushort_t;
typedef __attribute__((ext_vector_type(8))) short bf16x8;
typedef __attribute__((ext_vector_type(4))) float floatx4;

__device__ __forceinline__ float u2f(ushort_t u) {
  return __uint_as_float(((unsigned int)u) << 16);
}
__device__ __forceinline__ ushort_t f2u(float f) {
  __hip_bfloat16 h = __float2bfloat16(f);
  return *(ushort_t*)&h;
}

// ---------------------------------------------------------------------------
// K0: dtype-normalization to fp32. Proven.
// ---------------------------------------------------------------------------
#define NSEG 30
struct CvtArgs {
  const void* src[NSEG];
  int cnt[NSEG];
  int off[NSEG];
};

__global__ __launch_bounds__(256) void cvt_kernel(CvtArgs a, float* __restrict__ dst,
                                                  const ushort_t* __restrict__ probe) {
  const bool f32 = (probe[0] == 0);
  const int gid = blockIdx.x * 256 + threadIdx.x;
  const int gsz = gridDim.x * 256;
  for (int s = 0; s < NSEG; ++s) {
    float* d = dst + a.off[s];
    const int n = a.cnt[s];
    if (f32) {
      const float* sp = (const float*)a.src[s];
      for (int i = gid; i < n; i += gsz) d[i] = sp[i];
    } else {
      const ushort_t* sp = (const ushort_t*)a.src[s];
      for (int i = gid; i < n; i += gsz) d[i] = u2f(sp[i]);
    }
  }
}

// K0b: bf16 copies of attn_w1 (512x256), attn_w2 (256x512), pos_w2 (256x64).
__global__ __launch_bounds__(256) void cvtw_kernel(
    const float* __restrict__ w1f, const float* __restrict__ w2f,
    const float* __restrict__ w2pf,
    ushort_t* __restrict__ w1b, ushort_t* __restrict__ w2b,
    ushort_t* __restrict__ w2pb) {
  int i = blockIdx.x * 256 + threadIdx.x;   // grid covers 131072
  w1b[i] = f2u(w1f[i]);
  w2b[i] = f2u(w2f[i]);
  if (i < DD * PHH) w2pb[i] = f2u(w2pf[i]);
}

// ---------------------------------------------------------------------------
// K0c: prep — folded matrices for the distributed gemm1:
//   WW[a][p]  = sum_d W1[a][d]*W2p[d][p]              (512x64, bf16)
//   WQH[a][c] = sum_d W1[a][d]*Wq[d][c]               (512x128, bf16)
//   ball[a]   = sum_d W1[a][d]*(b_query[d]+pos_b2[d]) + attn_b1[a]  (f32)
// ---------------------------------------------------------------------------
__global__ __launch_bounds__(128) void prep_kernel(
    const float* __restrict__ w1f, const float* __restrict__ w2pf,
    const float* __restrict__ wqf, const float* __restrict__ bqf,
    const float* __restrict__ b2f, const float* __restrict__ ab1f,
    ushort_t* __restrict__ WWb, ushort_t* __restrict__ WQHb,
    float* __restrict__ ballf) {
  __shared__ float s_w1[DD];
  const int a = blockIdx.x;        // 512
  const int t = threadIdx.x;       // 128
  s_w1[t] = w1f[a * DD + t];
  s_w1[t + 128] = w1f[a * DD + t + 128];
  __syncthreads();
  {
    float acc = 0.f;
    for (int d = 0; d < DD; ++d) acc += s_w1[d] * wqf[d * CF + t];
    WQHb[a * CF + t] = f2u(acc);
  }
  if (t < PHH) {
    float acc = 0.f;
    for (int d = 0; d < DD; ++d) acc += s_w1[d] * w2pf[d * PHH + t];
    WWb[a * PHH + t] = f2u(acc);
  }
  if (t == 0) {
    float acc = ab1f[a];
    for (int d = 0; d < DD; ++d) acc += s_w1[d] * (bqf[d] + b2f[d]);
    ballf[a] = acc;
  }
}

// ---------------------------------------------------------------------------
// K1: fused value -> key/val (bf16 out). Proven.
// ---------------------------------------------------------------------------
__global__ __launch_bounds__(256) void vkv_kernel(
    const float* __restrict__ w_start, const float* __restrict__ b_start,
    const float* __restrict__ w_key, const float* __restrict__ b_key,
    const float* __restrict__ w_value, const float* __restrict__ b_value,
    const float* __restrict__ seed_fea,
    ushort_t* __restrict__ key_b, ushort_t* __restrict__ val_b) {
  __shared__ __align__(16) float s_val[4][DD];
  const int tid = threadIdx.x;              // = d
  const int b = blockIdx.x >> 8;
  const int m0 = (blockIdx.x & 255) << 2;

  float a0 = b_start[tid], a1 = a0, a2 = a0, a3 = a0;
  {
    const float* wrow = w_start + tid * CF;
    const float* colb = seed_fea + b * CF * MS + m0;
    for (int c = 0; c < CF; c += 4) {
      float4 w = *(const float4*)(wrow + c);
      float4 f0 = *(const float4*)(colb + (c + 0) * MS);
      float4 f1 = *(const float4*)(colb + (c + 1) * MS);
      float4 f2 = *(const float4*)(colb + (c + 2) * MS);
      float4 f3 = *(const float4*)(colb + (c + 3) * MS);
      a0 += w.x * f0.x + w.y * f1.x + w.z * f2.x + w.w * f3.x;
      a1 += w.x * f0.y + w.y * f1.y + w.z * f2.y + w.w * f3.y;
      a2 += w.x * f0.z + w.y * f1.z + w.z * f2.z + w.w * f3.z;
      a3 += w.x * f0.w + w.y * f1.w + w.z * f2.w + w.w * f3.w;
    }
  }
  s_val[0][tid] = a0; s_val[1][tid] = a1; s_val[2][tid] = a2; s_val[3][tid] = a3;
  __syncthreads();

  float ak[4], av[4];
#pragma unroll
  for (int i = 0; i < 4; ++i) { ak[i] = b_key[tid]; av[i] = b_value[tid]; }
  {
    const float* kr = w_key + tid * DD;
    const float* vr = w_value + tid * DD;
    for (int c = 0; c < DD; c += 4) {
      float4 ku = *(const float4*)(kr + c);
      float4 vu = *(const float4*)(vr + c);
      float4 v0 = *(const float4*)(&s_val[0][c]);
      float4 v1 = *(const float4*)(&s_val[1][c]);
      float4 v2 = *(const float4*)(&s_val[2][c]);
      float4 v3 = *(const float4*)(&s_val[3][c]);
      ak[0] += ku.x * v0.x + ku.y * v0.y + ku.z * v0.z + ku.w * v0.w;
      ak[1] += ku.x * v1.x + ku.y * v1.y + ku.z * v1.z + ku.w * v1.w;
      ak[2] += ku.x * v2.x + ku.y * v2.y + ku.z * v2.z + ku.w * v2.w;
      ak[3] += ku.x * v3.x + ku.y * v3.y + ku.z * v3.z + ku.w * v3.w;
      av[0] += vu.x * v0.x + vu.y * v0.y + vu.z * v0.z + vu.w * v0.w;
      av[1] += vu.x * v1.x + vu.y * v1.y + vu.z * v1.z + vu.w * v1.w;
      av[2] += vu.x * v2.x + vu.y * v2.y + vu.z * v2.z + vu.w * v2.w;
      av[3] += vu.x * v3.x + vu.y * v3.y + vu.z * v3.z + vu.w * v3.w;
    }
  }
#pragma unroll
  for (int i = 0; i < 4; ++i) {
    key_b[(b * MS + m0 + i) * DD + tid] = f2u(ak[i]);
    val_b[(b * MS + m0 + i) * DD + tid] = f2u(av[i]);
  }
}

// ---------------------------------------------------------------------------
// K1b: kh table — kh[b][m][a] = key[m] . W1[a]  (4096x512, bf16). Proven R9.
// ---------------------------------------------------------------------------
__global__ __launch_bounds__(256) void kh_kernel(
    const ushort_t* __restrict__ key_b, const ushort_t* __restrict__ w1b,
    ushort_t* __restrict__ khb) {
  __shared__ __align__(16) ushort_t s_key[16 * LKH];   // 8448 B
  const int tid = threadIdx.x;
  const int wv = tid >> 6, ln = tid & 63;
  const int qu = ln >> 4, l15 = ln & 15;
  const int b = blockIdx.x >> 6;
  const int m0 = (blockIdx.x & 63) << 4;
  {
    const int row = tid >> 4, seg = tid & 15;
    const ushort_t* src = key_b + (b * MS + m0 + row) * DD + seg * 16;
    ushort_t* dst = s_key + row * LKH + seg * 16;
    *(bf16x8*)(dst + 0) = *(const bf16x8*)(src + 0);
    *(bf16x8*)(dst + 8) = *(const bf16x8*)(src + 8);
  }
  __syncthreads();
  bf16x8 af[8];
#pragma unroll
  for (int ks = 0; ks < 8; ++ks)
    af[ks] = *(const bf16x8*)(s_key + l15 * LKH + ks * 32 + qu * 8);
  floatx4 acc[8];
#pragma unroll
  for (int nt = 0; nt < 8; ++nt) acc[nt] = (floatx4){0.f, 0.f, 0.f, 0.f};
#pragma unroll
  for (int ks = 0; ks < 8; ++ks)
#pragma unroll
    for (int nt = 0; nt < 8; ++nt) {
      bf16x8 bfr = *(const bf16x8*)(w1b + (wv * 128 + nt * 16 + l15) * DD + ks * 32 + qu * 8);
      acc[nt] = __builtin_amdgcn_mfma_f32_16x16x32_bf16(af[ks], bfr, acc[nt], 0, 0, 0);
    }
#pragma unroll
  for (int nt = 0; nt < 8; ++nt)
#pragma unroll
    for (int r = 0; r < 4; ++r)
      khb[(b * MS + m0 + qu * 4 + r) * AHH + wv * 128 + nt * 16 + l15] = f2u(acc[nt][r]);
}

// ---------------------------------------------------------------------------
// K2: knn — WAVE-PER-QUERY, 8 queries/block, coalesced staging. Proven R6.
// ---------------------------------------------------------------------------
__global__ __launch_bounds__(512) void knn_kernel(
    const float* __restrict__ pos_flipped, const float* __restrict__ seed,
    int* __restrict__ idx_out) {
  __shared__ float s_p[MS * 3];              // 12288 B, flat xyz
  const int tid = threadIdx.x;
  const int wv = tid >> 6, ln = tid & 63;
  const int b = blockIdx.x >> 9;             // 512 blocks per batch
  const int q = ((blockIdx.x & 511) << 3) + wv;

  for (int i = tid; i < MS * 3; i += 512) s_p[i] = seed[b * MS * 3 + i];
  __syncthreads();

  const float qx = pos_flipped[(b * NQ + q) * 3 + 0];
  const float qy = pos_flipped[(b * NQ + q) * 3 + 1];
  const float qz = pos_flipped[(b * NQ + q) * 3 + 2];
  const float q2 = qx * qx + qy * qy + qz * qz;

  unsigned long long key[16];
#pragma unroll
  for (int t = 0; t < 16; ++t) {
    int j = ln + (t << 6);
    float x = s_p[j * 3 + 0], y = s_p[j * 3 + 1], z = s_p[j * 3 + 2];
    float r2 = x * x + y * y + z * z;
    float dist = q2 + r2 - 2.0f * (qx * x + qy * y + qz * z);
    unsigned u = __float_as_uint(dist);
    u ^= (u >> 31) ? 0xFFFFFFFFu : 0x80000000u;   // monotone float->uint
    key[t] = ((unsigned long long)u << 10) | (unsigned)j;
  }

#pragma unroll 1
  for (int r = 0; r < KNN; ++r) {
    unsigned long long m = key[0];
#pragma unroll
    for (int t = 1; t < 16; ++t) m = (key[t] < m) ? key[t] : m;
#pragma unroll
    for (int off = 32; off >= 1; off >>= 1) {
      unsigned lo = (unsigned)m, hi = (unsigned)(m >> 32);
      unsigned olo = __shfl_xor((int)lo, off);
      unsigned ohi = __shfl_xor((int)hi, off);
      unsigned long long o = ((unsigned long long)ohi << 32) | olo;
      m = (o < m) ? o : m;
    }
    if (ln == 0) idx_out[(b * NQ + q) * KNN + r] = (int)(m & 1023u);
#pragma unroll
    for (int t = 0; t < 16; ++t) key[t] = (key[t] == m) ? ~0ull : key[t];
  }
}

// ---------------------------------------------------------------------------
// K3: FUSED pipeline — R13 (session best: fused 464 µs, total 732 µs):
// distributed-W1 gemm1 (K=64) + kh table + DOUBLE-BUFFERED s_hid (one barrier
// per nc). Macros not lambdas (R11: array-by-ref into lambda forces scratch).
// LDS 37.3 KB -> 4 blocks/CU (149.4 KB of 160). VGPR 64 + 64 AGPR, no spill.
// ---------------------------------------------------------------------------
#define DO_B(NCX, HID)                                                         \
  {                                                                            \
    const int nc_ = (NCX);                                                     \
    floatx4 accb[4];                                                           \
    _Pragma("unroll")                                                          \
    for (int mt = 0; mt < 4; ++mt) accb[mt] = (floatx4){0.f, 0.f, 0.f, 0.f};   \
    _Pragma("unroll")                                                          \
    for (int ks = 0; ks < 2; ++ks) {                                           \
      bf16x8 bw = *(const bf16x8*)(WWb + (nc_ * 64 + wv * 16 + l15) * PHH +    \
                                   ks * 32 + qu * 8);                          \
      _Pragma("unroll")                                                        \
      for (int mt = 0; mt < 4; ++mt) {                                         \
        bf16x8 af = *(const bf16x8*)(s_phb + (mt * 16 + l15) * LDH +           \
                                     ks * 32 + qu * 8);                        \
        accb[mt] = __builtin_amdgcn_mfma_f32_16x16x32_bf16(af, bw, accb[mt],   \
                                                           0, 0, 0);           \
      }                                                                        \
    }                                                                          \
    const int a_ = nc_ * 64 + wv * 16 + l15;                                   \
    float inv_ = attn_g1[a_] * rsqrtf(attn_var1[a_] + EPSBN);                  \
    float offc_ = ballf[a_] * inv_ + attn_beta1[a_] - attn_mu1[a_] * inv_;     \
    _Pragma("unroll")                                                          \
    for (int mt = 0; mt < 4; ++mt) {                                           \
      const float qhv_ = s_qh[mt * AHH + a_];                                  \
      _Pragma("unroll")                                                        \
      for (int r = 0; r < 4; ++r) {                                            \
        const int row_ = mt * 16 + qu * 4 + r;                                 \
        float khv_ = u2f(khb[(b * MS + s_idx[row_]) * AHH + a_]);              \
        float raw_ = accb[mt][r] + qhv_ - khv_;                                \
        (HID)[row_ * LDH + wv * 16 + l15] =                                    \
            f2u(fmaxf(raw_ * inv_ + offc_, 0.0f));                             \
      }                                                                        \
    }                                                                          \
  }

#define DO_C(NCX, HID)                                                         \
  {                                                                            \
    const int nc_ = (NCX);                                                     \
    _Pragma("unroll")                                                          \
    for (int ks = 0; ks < 2; ++ks) {                                           \
      bf16x8 af2[4];                                                           \
      _Pragma("unroll")                                                        \
      for (int mt = 0; mt < 4; ++mt)                                           \
        af2[mt] = *(const bf16x8*)((HID) + (mt * 16 + l15) * LDH +             \
                                   ks * 32 + qu * 8);                          \
      _Pragma("unroll")                                                        \
      for (int nt = 0; nt < 4; ++nt) {                                         \
        bf16x8 bfr = *(const bf16x8*)(w2b + (wv * 64 + nt * 16 + l15) * AHH +  \
                                      nc_ * 64 + ks * 32 + qu * 8);            \
        _Pragma("unroll")                                                      \
        for (int mt = 0; mt < 4; ++mt)                                         \
          accl[mt][nt] = __builtin_amdgcn_mfma_f32_16x16x32_bf16(              \
              af2[mt], bfr, accl[mt][nt], 0, 0, 0);                            \
      }                                                                        \
    }                                                                          \
  }

__global__ __launch_bounds__(256, 4) void fused_kernel(
    const float* __restrict__ pos, const float* __restrict__ seed,
    const void* __restrict__ fea_raw,
    const float* __restrict__ pos_w1, const float* __restrict__ pos_b1,
    const float* __restrict__ pos_g1, const float* __restrict__ pos_beta1,
    const float* __restrict__ pos_mu1, const float* __restrict__ pos_var1,
    const ushort_t* __restrict__ w2pb, const float* __restrict__ pos_b2,
    const float* __restrict__ attn_g1, const float* __restrict__ attn_beta1,
    const float* __restrict__ attn_mu1, const float* __restrict__ attn_var1,
    const float* __restrict__ ballf,
    const ushort_t* __restrict__ WWb, const ushort_t* __restrict__ WQHb,
    const ushort_t* __restrict__ w2b, const ushort_t* __restrict__ khb,
    const ushort_t* __restrict__ val_b,
    const int* __restrict__ idx_in,
    const float* __restrict__ w_end, const float* __restrict__ b_end,
    void* __restrict__ out_raw, const ushort_t* __restrict__ probe) {
  __shared__ __align__(16) ushort_t s_phb[64 * LDH];   // 9216 B (alive to AGG)
  __shared__ __align__(16) ushort_t s_hid0[64 * LDH];  // 9216 B (dbuf 0)
  __shared__ __align__(16) ushort_t s_hid1[64 * LDH];  // 9216 B (dbuf 1)
  __shared__ __align__(16) float s_qh[4 * AHH];        // 8192 B (aliased by s_agg)
  __shared__ __align__(16) ushort_t s_feab[4 * CF];    // 1024 B
  __shared__ float s_h[64 * 4];                        // 1024 B
  __shared__ int s_idx[64];                            //  256 B
  // total 37,344 B -> 4 blocks/CU (149.4 KB of 160)

  float* s_agg = s_qh;   // alias: s_qh dead after nc-loop

  const int tid = threadIdx.x;
  const int wv = tid >> 6;
  const int ln = tid & 63;
  const int qu = ln >> 4, l15 = ln & 15;
  const bool f32io = (probe[0] == 0);
  const int q0 = blockIdx.x * 4;            // 4 queries/block; batch never splits
  const int b = q0 >> 12;
  const int qn0 = q0 & (NQ - 1);

  // ---- P0: neighbor idx + h = [dis, rel] (tid<64) ; FEA stage (tid<128) ----
  if (tid < 64) {
    const int g = tid >> 4;
    const int qn = qn0 + g;
    const int j = idx_in[(q0 + g) * KNN + (tid & 15)];
    s_idx[tid] = j;
    float px = pos[(b * 3 + 0) * NQ + qn];
    float py = pos[(b * 3 + 1) * NQ + qn];
    float pz = pos[(b * 3 + 2) * NQ + qn];
    float rx = px - seed[(b * MS + j) * 3 + 0];
    float ry = py - seed[(b * MS + j) * 3 + 1];
    float rz = pz - seed[(b * MS + j) * 3 + 2];
    float dis = sqrtf(rx * rx + ry * ry + rz * rz);
    s_h[tid * 4 + 0] = dis;
    s_h[tid * 4 + 1] = rx;
    s_h[tid * 4 + 2] = ry;
    s_h[tid * 4 + 3] = rz;
  }
  if (tid < 128) {               // fea columns qn0..qn0+3 for channel c=tid
    const int c = tid;
    if (f32io) {
      const float* fc = (const float*)fea_raw + (size_t)b * CF * NQ + (size_t)c * NQ + qn0;
      float4 v = *(const float4*)fc;
      s_feab[0 * CF + c] = f2u(v.x);
      s_feab[1 * CF + c] = f2u(v.y);
      s_feab[2 * CF + c] = f2u(v.z);
      s_feab[3 * CF + c] = f2u(v.w);
    } else {
      const ushort_t* fc = (const ushort_t*)fea_raw + (size_t)b * CF * NQ + (size_t)c * NQ + qn0;
      unsigned long long v = *(const unsigned long long*)fc;
      s_feab[0 * CF + c] = (ushort_t)(v);
      s_feab[1 * CF + c] = (ushort_t)(v >> 16);
      s_feab[2 * CF + c] = (ushort_t)(v >> 32);
      s_feab[3 * CF + c] = (ushort_t)(v >> 48);
    }
  }
  __syncthreads();

  // ---- P1: s_phb = relu(BN(pos_w1 @ h)) (bf16), 64 rows x 64 p ----
  {
    const int p = tid & 63, kb = tid >> 6;
    float4 w = *(const float4*)(pos_w1 + p * 4);
    float inv = pos_g1[p] * rsqrtf(pos_var1[p] + EPSBN);
    float off = pos_b1[p] * inv + pos_beta1[p] - pos_mu1[p] * inv;
#pragma unroll
    for (int i = 0; i < 16; ++i) {
      int gk = kb * 16 + i;
      float raw = w.x * s_h[gk * 4 + 0] + w.y * s_h[gk * 4 + 1] +
                  w.z * s_h[gk * 4 + 2] + w.w * s_h[gk * 4 + 3];
      s_phb[gk * LDH + p] = f2u(fmaxf(raw * inv + off, 0.0f));
    }
  }

  // ---- QH: qh[4][512] = fea(4x128) @ WQH^T via MFMA (32 MFMA/wave) ----
  {
    bf16x8 afq[4];
#pragma unroll
    for (int ks = 0; ks < 4; ++ks) {
      if (l15 < 4) afq[ks] = *(const bf16x8*)(s_feab + l15 * CF + ks * 32 + qu * 8);
      else afq[ks] = (bf16x8){0, 0, 0, 0, 0, 0, 0, 0};
    }
    floatx4 aq[8];
#pragma unroll
    for (int nt = 0; nt < 8; ++nt) aq[nt] = (floatx4){0.f, 0.f, 0.f, 0.f};
#pragma unroll
    for (int ks = 0; ks < 4; ++ks)
#pragma unroll
      for (int nt = 0; nt < 8; ++nt) {
        bf16x8 bfr = *(const bf16x8*)(WQHb + (nt * 64 + wv * 16 + l15) * CF + ks * 32 + qu * 8);
        aq[nt] = __builtin_amdgcn_mfma_f32_16x16x32_bf16(afq[ks], bfr, aq[nt], 0, 0, 0);
      }
    if (qu == 0) {
#pragma unroll
      for (int nt = 0; nt < 8; ++nt)
#pragma unroll
        for (int r = 0; r < 4; ++r)
          s_qh[r * AHH + nt * 64 + wv * 16 + l15] = aq[nt][r];
    }
  }
  __syncthreads();

  // ---- nc-loop (dbuf): prologue B(0); then {B(nc+1) || C(nc); bar} x8 ----
  floatx4 accl[4][4];  // logits: rows mt*16+qu*4+r, cols wv*64+nt*16+l15
#pragma unroll
  for (int mt = 0; mt < 4; ++mt)
#pragma unroll
    for (int nt = 0; nt < 4; ++nt) accl[mt][nt] = (floatx4){0.f, 0.f, 0.f, 0.f};

  DO_B(0, s_hid0);
  __syncthreads();

#pragma unroll 1
  for (int nc = 0; nc < 8; ++nc) {
    ushort_t* cur = (nc & 1) ? s_hid1 : s_hid0;
    ushort_t* nxt = (nc & 1) ? s_hid0 : s_hid1;
    if (nc < 7) DO_B(nc + 1, nxt);
    DO_C(nc, cur);
    __syncthreads();   // B(nc+1) visible for next C; C(nc) done before B(nc+2)
  }

  // ---- AGG: softmax over k + pe RECOMPUTE (MFMA from s_phb) + val gather ----
#pragma unroll
  for (int nt = 0; nt < 4; ++nt) {
    const int c = wv * 64 + nt * 16 + l15;
    floatx4 ap[4];
#pragma unroll
    for (int mt = 0; mt < 4; ++mt) ap[mt] = (floatx4){0.f, 0.f, 0.f, 0.f};
#pragma unroll
    for (int ks = 0; ks < 2; ++ks) {
      bf16x8 bfr = *(const bf16x8*)(w2pb + c * PHH + ks * 32 + qu * 8);
#pragma unroll
      for (int mt = 0; mt < 4; ++mt) {
        bf16x8 af = *(const bf16x8*)(s_phb + (mt * 16 + l15) * LDH + ks * 32 + qu * 8);
        ap[mt] = __builtin_amdgcn_mfma_f32_16x16x32_bf16(af, bfr, ap[mt], 0, 0, 0);
      }
    }
    const float b2v = pos_b2[c];
#pragma unroll
    for (int mt = 0; mt < 4; ++mt) {
      float l0 = accl[mt][nt][0], l1 = accl[mt][nt][1];
      float l2 = accl[mt][nt][2], l3 = accl[mt][nt][3];
      float mx = fmaxf(fmaxf(l0, l1), fmaxf(l2, l3));
      mx = fmaxf(mx, __shfl_xor(mx, 16));
      mx = fmaxf(mx, __shfl_xor(mx, 32));
      float e0 = expf(l0 - mx), e1 = expf(l1 - mx);
      float e2 = expf(l2 - mx), e3 = expf(l3 - mx);
      float s = e0 + e1 + e2 + e3;
      s += __shfl_xor(s, 16);
      s += __shfl_xor(s, 32);
      const int row0 = mt * 16 + qu * 4;
      float v0 = u2f(val_b[(b * MS + s_idx[row0 + 0]) * DD + c]);
      float v1 = u2f(val_b[(b * MS + s_idx[row0 + 1]) * DD + c]);
      float v2 = u2f(val_b[(b * MS + s_idx[row0 + 2]) * DD + c]);
      float v3 = u2f(val_b[(b * MS + s_idx[row0 + 3]) * DD + c]);
      float p = e0 * (v0 + ap[mt][0] + b2v) + e1 * (v1 + ap[mt][1] + b2v) +
                e2 * (v2 + ap[mt][2] + b2v) + e3 * (v3 + ap[mt][3] + b2v);
      p += __shfl_xor(p, 16);
      p += __shfl_xor(p, 32);
      if (ln < 16) s_agg[mt * DD + c] = p / s;   // into s_qh alias
    }
  }
  __syncthreads();

  // ---- OUT: out = w_end @ agg + b_end + fea (2 queries per thread) ----
  {
    const int c = tid & 127;
    const int qh = tid >> 7;  // handles queries qh and qh+2
    float acc0 = 0.0f, acc1 = 0.0f;
    const float* wr = w_end + c * DD;
    for (int d = 0; d < DD; d += 4) {
      float4 w4 = *(const float4*)(wr + d);
      float4 a0 = *(const float4*)(s_agg + (qh + 0) * DD + d);
      float4 a1 = *(const float4*)(s_agg + (qh + 2) * DD + d);
      acc0 += w4.x * a0.x + w4.y * a0.y + w4.z * a0.z + w4.w * a0.w;
      acc1 += w4.x * a1.x + w4.y * a1.y + w4.z * a1.z + w4.w * a1.w;
    }
    const float be = b_end[c];
#pragma unroll
    for (int t = 0; t < 2; ++t) {
      const int q = qh + t * 2;
      const float accv = (t == 0) ? acc0 : acc1;
      const int oidx = (b * CF + c) * NQ + qn0 + q;
      float fres = f32io ? ((const float*)fea_raw)[oidx]
                         : u2f(((const ushort_t*)fea_raw)[oidx]);
      float v = accv + be + fres;
      if (f32io) ((float*)out_raw)[oidx] = v;
      else ((ushort_t*)out_raw)[oidx] = f2u(v);
    }
  }
}

// ---------------------------------------------------------------------------
extern "C" void kernel_launch(void* const* d_in, const int* in_sizes, int n_in,
                              void* d_out, int out_size, void* d_ws, size_t ws_size,
                              hipStream_t stream) {
  (void)in_sizes; (void)n_in; (void)out_size; (void)ws_size;

  // ws layout (float offsets)
  float* wsf = (float*)d_ws;
  ushort_t* key_b = (ushort_t*)wsf;                 // 1,048,576 ush
  ushort_t* val_b = (ushort_t*)(wsf + 524288);      // 1,048,576 ush
  int*      idxw  = (int*)(wsf + 1048576);          //   262,144 i
  float*    nrm   = wsf + 1310720;                  // 1,147,584 f
  ushort_t* w1b   = (ushort_t*)(wsf + 2458304);     //   131,072 ush
  ushort_t* w2b   = (ushort_t*)(wsf + 2523840);     //   131,072 ush
  ushort_t* w2pb  = (ushort_t*)(wsf + 2589376);     //    16,384 ush
  ushort_t* khb   = (ushort_t*)(wsf + 2613952);     // 2,097,152 ush (4 MB)
  ushort_t* WWb   = (ushort_t*)(wsf + 3662528);     //    32,768 ush
  ushort_t* WQHb  = (ushort_t*)(wsf + 3678912);     //    65,536 ush
  float*    ballf = wsf + 3711680;                  //       512 f
  // end: 3,712,192 f = 14,848,768 B

  static const int seg_in[NSEG] = {0, 1, 3, 4, 5, 6, 7, 8, 9, 10, 11, 12, 13, 14,
                                   15, 16, 17, 18, 19, 20, 21, 22, 23, 24, 25, 26,
                                   27, 28, 29, 30};
  static const int seg_cnt[NSEG] = {
      49152, 49152, 12288, 524288, 32768, 256, 65536, 256, 65536, 256,
      32768, 256, 256, 64, 64, 64, 64, 64, 16384, 256,
      131072, 512, 512, 512, 512, 512, 131072, 256, 32768, 128};
  static const int seg_off[NSEG] = {
      0, 49152, 98304, 110592, 634880, 667648, 667904, 733440, 733696, 799232,
      799488, 832256, 832512, 832768, 832832, 832896, 832960, 833024, 833088, 849472,
      849728, 980800, 981312, 981824, 982336, 982848, 983360, 1114432, 1114688, 1147456};

  CvtArgs ca;
  for (int s = 0; s < NSEG; ++s) {
    ca.src[s] = d_in[seg_in[s]];
    ca.cnt[s] = seg_cnt[s];
    ca.off[s] = seg_off[s];
  }
  const ushort_t* probe = (const ushort_t*)d_in[18];  // pos_var1 (== 1.0)

  const float* posN      = nrm + 0;
  const float* pos_flipN = nrm + 49152;
  const float* seedN     = nrm + 98304;
  const float* seed_feaN = nrm + 110592;
  const float* w_startN  = nrm + 634880;
  const float* b_startN  = nrm + 667648;
  const float* w_keyN    = nrm + 667904;
  const float* b_keyN    = nrm + 733440;
  const float* w_valueN  = nrm + 733696;
  const float* b_valueN  = nrm + 799232;
  const float* w_queryN  = nrm + 799488;
  const float* b_queryN  = nrm + 832256;
  const float* pos_w1N   = nrm + 832512;
  const float* pos_b1N   = nrm + 832768;
  const float* pos_g1N   = nrm + 832832;
  const float* pos_beta1N= nrm + 832896;
  const float* pos_mu1N  = nrm + 832960;
  const float* pos_var1N = nrm + 833024;
  const float* pos_w2N   = nrm + 833088;
  const float* pos_b2N   = nrm + 849472;
  const float* attn_w1N  = nrm + 849728;
  const float* attn_b1N  = nrm + 980800;
  const float* attn_g1N  = nrm + 981312;
  const float* attn_beta1N = nrm + 981824;
  const float* attn_mu1N = nrm + 982336;
  const float* attn_var1N= nrm + 982848;
  const float* attn_w2N  = nrm + 983360;
  const float* w_endN    = nrm + 1114688;
  const float* b_endN    = nrm + 1147456;

  cvt_kernel<<<512, 256, 0, stream>>>(ca, nrm, probe);
  cvtw_kernel<<<512, 256, 0, stream>>>(attn_w1N, attn_w2N, pos_w2N,
                                       w1b, w2b, w2pb);
  prep_kernel<<<512, 128, 0, stream>>>(attn_w1N, pos_w2N, w_queryN,
                                       b_queryN, pos_b2N, attn_b1N,
                                       WWb, WQHb, ballf);
  vkv_kernel<<<BB * MS / 4, 256, 0, stream>>>(w_startN, b_startN, w_keyN, b_keyN,
                                              w_valueN, b_valueN, seed_feaN,
                                              key_b, val_b);
  kh_kernel<<<BB * MS / 16, 256, 0, stream>>>(key_b, w1b, khb);
  knn_kernel<<<BB * NQ / 8, 512, 0, stream>>>(pos_flipN, seedN, idxw);

  fused_kernel<<<BB * NQ / 4, 256, 0, stream>>>(
      posN, seedN, d_in[2],
      pos_w1N, pos_b1N, pos_g1N, pos_beta1N, pos_mu1N, pos_var1N,
      w2pb, pos_b2N,
      attn_g1N, attn_beta1N, attn_mu1N, attn_var1N,
      ballf, WWb, WQHb, w2b, khb, val_b, idxw,
      w_endN, b_endN, d_out, probe);
}